// Round 8
// baseline (212.351 us; speedup 1.0000x reference)
//
#include <hip/hip_runtime.h>

#define NN 4096
#define NFEAT 512
#define NHID 64
#define H1 8
#define NCLS 16
#define BND 40.0f   // static bound, layer-2 path only
#define VSTR 72     // f16 elems per vT row: 144B rows, 16B-aligned
#define FSCL 4096.0f

typedef short bf16x8 __attribute__((ext_vector_type(8)));
typedef _Float16 f16x8 __attribute__((ext_vector_type(8)));
typedef _Float16 h2 __attribute__((ext_vector_type(2)));
typedef __fp16 fp16v2 __attribute__((ext_vector_type(2)));
typedef float f32x4 __attribute__((ext_vector_type(4)));

__device__ __forceinline__ unsigned short f2bf(float f) {
    unsigned u = __float_as_uint(f);
    u += 0x7fffu + ((u >> 16) & 1u);
    return (unsigned short)(u >> 16);
}
__device__ __forceinline__ float leaky(float v) { return fmaxf(v, 0.2f * v); }
__device__ __forceinline__ unsigned pkbf(float lo, float hi) {
    return __builtin_amdgcn_perm(__float_as_uint(hi) + 0x8000u,
                                 __float_as_uint(lo) + 0x8000u, 0x07060302u);
}
__device__ __forceinline__ unsigned pkh(float lo, float hi) {
    union { fp16v2 h; unsigned u; } c;
    c.h = __builtin_amdgcn_cvt_pkrtz(lo, hi);
    return c.u;
}
__device__ __forceinline__ h2 uash(unsigned u) { union { unsigned u; h2 h; } c; c.u = u; return c.h; }
__device__ __forceinline__ unsigned hasu(h2 h) { union { unsigned u; h2 h; } c; c.h = h; return c.u; }
__device__ __forceinline__ bf16x8 mk8(unsigned a, unsigned b, unsigned c, unsigned d) {
    union { unsigned u[4]; bf16x8 v; } cv;
    cv.u[0] = a; cv.u[1] = b; cv.u[2] = c; cv.u[3] = d; return cv.v;
}
__device__ __forceinline__ f16x8 mk8h(unsigned a, unsigned b, unsigned c, unsigned d) {
    union { unsigned u[4]; f16x8 v; } cv;
    cv.u[0] = a; cv.u[1] = b; cv.u[2] = c; cv.u[3] = d; return cv.v;
}

// ---------------------------------------------------------------------------
// Triple-role prep: [0,NN) adj pack; [NN,NN+64) W1 -> f16 frag-major;
// [NN+64, NN+64+512) x -> xh f16.
// ---------------------------------------------------------------------------
__global__ __launch_bounds__(256)
void k_prep(const int* __restrict__ adj, unsigned long long* __restrict__ bits,
            const float* __restrict__ W1, unsigned short* __restrict__ w1f,
            const float* __restrict__ x, unsigned short* __restrict__ xh)
{
    __shared__ float wt[64][65];
    const int t = threadIdx.x, bx = blockIdx.x;
    if (bx < NN) {
        const int wv = t >> 6, lane = t & 63;
        const int* ap = adj + (size_t)bx * NN;
        for (int w = wv; w < 64; w += 4) {
            unsigned long long m = __ballot(ap[w * 64 + lane] > 0);
            if (lane == 0) bits[(size_t)bx * 64 + w] = m;
        }
        return;
    }
    if (bx >= NN + 64) {   // x -> f16
        const int b = bx - NN - 64;
        #pragma unroll
        for (int i = 0; i < 4; ++i) {
            const int f4 = b * 1024 + i * 256 + t;
            const float4 v = ((const float4*)x)[f4];
            uint2 w; w.x = pkh(v.x, v.y); w.y = pkh(v.z, v.w);
            ((uint2*)xh)[f4] = w;
        }
        return;
    }
    const int kt = (bx - NN) & 7, h = (bx - NN) >> 3;
    #pragma unroll
    for (int i = 0; i < 4; ++i) {
        const int f = t + 256 * i;
        const int r = f >> 4, c4 = f & 15;
        const float4 v = *(const float4*)(W1 + ((size_t)(h * NFEAT) + kt * 64 + r) * NHID + c4 * 4);
        wt[r][c4 * 4 + 0] = v.x; wt[r][c4 * 4 + 1] = v.y;
        wt[r][c4 * 4 + 2] = v.z; wt[r][c4 * 4 + 3] = v.w;
    }
    __syncthreads();
    #pragma unroll
    for (int s = 0; s < 2; ++s) {
        const int o = t + s * 256;
        const int kg2 = o >> 8, rem = o & 255;
        const int nt = rem >> 6, lane2 = rem & 63;
        const int qq = lane2 >> 4, nn = lane2 & 15;
        const int kl = kg2 * 32 + qq * 8;
        const int c = nt * 16 + nn;
        uint4 w;
        w.x = pkh(wt[kl + 0][c], wt[kl + 1][c]);
        w.y = pkh(wt[kl + 2][c], wt[kl + 3][c]);
        w.z = pkh(wt[kl + 4][c], wt[kl + 5][c]);
        w.w = pkh(wt[kl + 6][c], wt[kl + 7][c]);
        *(uint4*)(w1f + (((size_t)h * 16 + kt * 2 + kg2) * 4 + nt) * 512 + lane2 * 8) = w;
    }
}

// ---------------------------------------------------------------------------
// feats1 = xh @ W1 (f16 MFMA) -> f1bT (f16, transposed) + s1/nb1 fp32.
// grid (64,8), 256 thr.
// ---------------------------------------------------------------------------
__global__ __launch_bounds__(256)
void k_feats1(const unsigned short* __restrict__ xh, const unsigned short* __restrict__ w1f,
              const float* __restrict__ as1, const float* __restrict__ an1,
              unsigned short* __restrict__ f1bT, float* __restrict__ s1, float* __restrict__ nb1)
{
    const int t = threadIdx.x, wv = t >> 6, lane = t & 63;
    const int q = lane >> 4, n = lane & 15;
    const int h = blockIdx.y, R0 = blockIdx.x * 64;
    const int row = R0 + wv * 16 + n;
    const unsigned short* ap = xh + (size_t)row * NFEAT;
    const unsigned short* wp = w1f + (size_t)h * 16 * 4 * 512 + lane * 8;
    f32x4 acc[4] = {{0.f,0.f,0.f,0.f},{0.f,0.f,0.f,0.f},{0.f,0.f,0.f,0.f},{0.f,0.f,0.f,0.f}};
    #pragma unroll 4
    for (int kg = 0; kg < 16; ++kg) {
        const f16x8 af = *(const f16x8*)(ap + kg * 32 + q * 8);
        #pragma unroll
        for (int nt = 0; nt < 4; ++nt) {
            const f16x8 bf = *(const f16x8*)(wp + (size_t)(kg * 4 + nt) * 512);
            acc[nt] = __builtin_amdgcn_mfma_f32_16x16x32_f16(af, bf, acc[nt], 0, 0, 0);
        }
    }
    #pragma unroll
    for (int nt = 0; nt < 4; ++nt) {
        uint2 w;
        w.x = pkh(acc[nt][0], acc[nt][1]);
        w.y = pkh(acc[nt][2], acc[nt][3]);
        *(uint2*)(f1bT + ((size_t)h * NHID + nt * 16 + n) * NN + R0 + wv * 16 + q * 4) = w;
    }
    float asv[4], anv[4];
    #pragma unroll
    for (int nt = 0; nt < 4; ++nt) {
        asv[nt] = as1[h * NHID + nt * 16 + n];
        anv[nt] = an1[h * NHID + nt * 16 + n];
    }
    #pragma unroll
    for (int i = 0; i < 4; ++i) {
        float ps = acc[0][i]*asv[0] + acc[1][i]*asv[1] + acc[2][i]*asv[2] + acc[3][i]*asv[3];
        float pn = acc[0][i]*anv[0] + acc[1][i]*anv[1] + acc[2][i]*anv[2] + acc[3][i]*anv[3];
        #pragma unroll
        for (int off = 8; off > 0; off >>= 1) {
            ps += __shfl_xor(ps, off, 64);
            pn += __shfl_xor(pn, off, 64);
        }
        if (n == 0) {
            const int idx = R0 + wv * 16 + q * 4 + i;
            s1[h * NN + idx] = ps;
            nb1[h * NN + idx] = pn;
        }
    }
}

// ---------------------------------------------------------------------------
// Per-head max over nb1 + scaled f16 factors F1h/F2h. grid H1 blocks.
// ---------------------------------------------------------------------------
__global__ __launch_bounds__(256)
void k_fact1(const float* __restrict__ nb1, unsigned short* __restrict__ F1h,
             unsigned short* __restrict__ F2h, float* __restrict__ nbmax)
{
    const int b = blockIdx.x, t = threadIdx.x;
    const float* p = nb1 + (size_t)b * NN;
    float m = -INFINITY;
    for (int i = t; i < NN; i += 256) m = fmaxf(m, p[i]);
    #pragma unroll
    for (int off = 32; off > 0; off >>= 1) m = fmaxf(m, __shfl_xor(m, off, 64));
    __shared__ float sm[4];
    __shared__ float smx;
    if ((t & 63) == 0) sm[t >> 6] = m;
    __syncthreads();
    if (t == 0) {
        const float mm = fmaxf(fmaxf(sm[0], sm[1]), fmaxf(sm[2], sm[3]));
        smx = mm; nbmax[b] = mm;
    }
    __syncthreads();
    const float mx = smx;
    for (int i = t * 2; i < NN; i += 512) {
        const float d0 = p[i] - mx, d1 = p[i + 1] - mx;
        ((unsigned*)F1h)[((size_t)b * NN + i) >> 1] = pkh(FSCL * __expf(d0), FSCL * __expf(d1));
        ((unsigned*)F2h)[((size_t)b * NN + i) >> 1] = pkh(FSCL * __expf(0.2f * d0), FSCL * __expf(0.2f * d1));
    }
}

// ---------------------------------------------------------------------------
// Layer-1 aggregation, packed-f16 score pipeline + f16 MFMA.
// 512 thr = 8 waves = (rg) row-group of 32 x (jq) j-quarter; 2 A-frags/wave.
// ---------------------------------------------------------------------------
__global__ __launch_bounds__(512, 4)
void k_gat1(const unsigned short* __restrict__ f1bT, const float* __restrict__ s1,
            const unsigned short* __restrict__ F1h, const unsigned short* __restrict__ F2h,
            const unsigned long long* __restrict__ abits, const float* __restrict__ b1,
            const float* __restrict__ nbmax1, unsigned short* __restrict__ hcatb)
{
    __shared__ __align__(16) char smem[4 * 2 * 64 * VSTR * 2];   // 73728 B
    unsigned short* vT = (unsigned short*)smem;

    const int t = threadIdx.x, wv = t >> 6, lane = t & 63;
    const int q = lane >> 4, n = lane & 15;
    const int rg = wv >> 2, jq = wv & 3;
    const int h = blockIdx.y, R0 = blockIdx.x * 64;
    const int rowA = R0 + rg * 32 + n;
    const int rowB = rowA + 16;
    const float mh = nbmax1[h];
    const float vA = s1[h * NN + rowA] + mh, mhA = leaky(vA);
    const float vB = s1[h * NN + rowB] + mh, mhB = leaky(vB);
    const float E1Af = __expf(vA - mhA), E2Af = __expf(0.2f * vA - mhA);
    const float E1Bf = __expf(vB - mhB), E2Bf = __expf(0.2f * vB - mhB);
    const h2 E1A = {(_Float16)E1Af, (_Float16)E1Af};
    const h2 E2A = {(_Float16)E2Af, (_Float16)E2Af};
    const h2 E1B = {(_Float16)E1Bf, (_Float16)E1Bf};
    const h2 E2B = {(_Float16)E2Bf, (_Float16)E2Bf};
    const unsigned long long* arowA = abits + (size_t)rowA * 64;
    const unsigned long long* arowB = abits + (size_t)rowB * 64;
    const unsigned short* F1p = F1h + (size_t)h * NN;
    const unsigned short* F2p = F2h + (size_t)h * NN;

    const int stile = t >> 7;
    const int sc0 = (t & 127) >> 3, sj8 = t & 7;
    const unsigned short* sbase = f1bT + (size_t)h * NHID * NN + (size_t)sc0 * NN + sj8 * 8;
    const int dof = sc0 * VSTR + sj8 * 8;

    f32x4 accA[4] = {{0.f,0.f,0.f,0.f},{0.f,0.f,0.f,0.f},{0.f,0.f,0.f,0.f},{0.f,0.f,0.f,0.f}};
    f32x4 accB[4] = {{0.f,0.f,0.f,0.f},{0.f,0.f,0.f,0.f},{0.f,0.f,0.f,0.f},{0.f,0.f,0.f,0.f}};
    float lsA = 0.f, lsB = 0.f;

    {   // preload it=0
        const int js = stile * 1024;
        int4 v0 = *(const int4*)(sbase + js);
        int4 v1 = *(const int4*)(sbase + (size_t)16 * NN + js);
        int4 v2 = *(const int4*)(sbase + (size_t)32 * NN + js);
        int4 v3 = *(const int4*)(sbase + (size_t)48 * NN + js);
        unsigned short* d = vT + (stile * 2 + 0) * (64 * VSTR) + dof;
        *(int4*)(d) = v0;
        *(int4*)(d + 16 * VSTR) = v1;
        *(int4*)(d + 32 * VSTR) = v2;
        *(int4*)(d + 48 * VSTR) = v3;
    }
    __syncthreads();

    for (int it = 0; it < 16; ++it) {
        const int db = it & 1;
        int4 p0, p1, p2, p3;
        if (it < 15) {
            const int js = stile * 1024 + (it + 1) * 64;
            p0 = *(const int4*)(sbase + js);
            p1 = *(const int4*)(sbase + (size_t)16 * NN + js);
            p2 = *(const int4*)(sbase + (size_t)32 * NN + js);
            p3 = *(const int4*)(sbase + (size_t)48 * NN + js);
        }
        const int j0 = jq * 1024 + it * 64;
        const unsigned long long aA = arowA[j0 >> 6];
        const unsigned long long aB = arowB[j0 >> 6];
        const unsigned short* tbase = vT + (jq * 2 + db) * (64 * VSTR);
        #pragma unroll
        for (int ch = 0; ch < 2; ++ch) {
            const int kb = ch * 32 + q * 8;
            const uint4 f1w = *(const uint4*)(F1p + j0 + kb);
            const uint4 f2w = *(const uint4*)(F2p + j0 + kb);
            const unsigned bA = (unsigned)(aA >> kb) & 0xffu;
            const unsigned bB = (unsigned)(aB >> kb) & 0xffu;
            unsigned uA[4], uB[4];
            h2 sA2 = {(_Float16)0, (_Float16)0};
            h2 sB2 = {(_Float16)0, (_Float16)0};
            #pragma unroll
            for (int jp = 0; jp < 4; ++jp) {
                const h2 f1 = uash(((const unsigned*)&f1w)[jp]);
                const h2 f2 = uash(((const unsigned*)&f2w)[jp]);
                const unsigned mA = ((bA >> (2*jp)) & 1u) * 0x3C00u
                                  + ((bA >> (2*jp+1)) & 1u) * 0x3C000000u;
                const unsigned mB = ((bB >> (2*jp)) & 1u) * 0x3C00u
                                  + ((bB >> (2*jp+1)) & 1u) * 0x3C000000u;
                h2 pA = __builtin_elementwise_max(E1A * f1, E2A * f2) * uash(mA);
                h2 pB = __builtin_elementwise_max(E1B * f1, E2B * f2) * uash(mB);
                sA2 += pA; sB2 += pB;
                uA[jp] = hasu(pA); uB[jp] = hasu(pB);
            }
            lsA += (float)sA2[0] + (float)sA2[1];
            lsB += (float)sB2[0] + (float)sB2[1];
            const f16x8 afA = mk8h(uA[0], uA[1], uA[2], uA[3]);
            const f16x8 afB = mk8h(uB[0], uB[1], uB[2], uB[3]);
            #pragma unroll
            for (int nt = 0; nt < 4; ++nt) {
                const f16x8 bf = *(const f16x8*)(tbase + (nt * 16 + n) * VSTR + kb);
                accA[nt] = __builtin_amdgcn_mfma_f32_16x16x32_f16(afA, bf, accA[nt], 0, 0, 0);
                accB[nt] = __builtin_amdgcn_mfma_f32_16x16x32_f16(afB, bf, accB[nt], 0, 0, 0);
            }
        }
        if (it < 15) {
            unsigned short* d = vT + (stile * 2 + (db ^ 1)) * (64 * VSTR) + dof;
            *(int4*)(d) = p0;
            *(int4*)(d + 16 * VSTR) = p1;
            *(int4*)(d + 32 * VSTR) = p2;
            *(int4*)(d + 48 * VSTR) = p3;
        }
        __syncthreads();
    }

    lsA += __shfl_xor(lsA, 16, 64); lsA += __shfl_xor(lsA, 32, 64);
    lsB += __shfl_xor(lsB, 16, 64); lsB += __shfl_xor(lsB, 32, 64);

    float* cmbf = (float*)smem;                 // [4][64][68]
    float* lwf  = (float*)(smem + 69632);       // [4][64]
    #pragma unroll
    for (int nt = 0; nt < 4; ++nt)
        #pragma unroll
        for (int i = 0; i < 4; ++i) {
            cmbf[((size_t)jq * 64 + rg * 32 + q * 4 + i) * 68 + nt * 16 + n] = accA[nt][i];
            cmbf[((size_t)jq * 64 + rg * 32 + 16 + q * 4 + i) * 68 + nt * 16 + n] = accB[nt][i];
        }
    if (q == 0) {
        lwf[jq * 64 + rg * 32 + n] = lsA;
        lwf[jq * 64 + rg * 32 + 16 + n] = lsB;
    }
    __syncthreads();

    const int col = t & 63, r8 = t >> 6;
    const float bv = b1[h * NHID + col];
    #pragma unroll
    for (int rr = 0; rr < 8; ++rr) {
        const int r = r8 * 8 + rr;
        float tot = 0.f, lt = 0.f;
        #pragma unroll
        for (int jj = 0; jj < 4; ++jj) {
            tot += cmbf[((size_t)jj * 64 + r) * 68 + col];
            lt  += lwf[jj * 64 + r];
        }
        hcatb[(size_t)(R0 + r) * (H1 * NHID) + h * NHID + col] =
            f2bf(fmaxf(tot / lt + bv, 0.f));    // relu; elu(x>=0)=x
    }
}

// ---------------------------------------------------------------------------
// feats2 = hcatb @ W2 (bf16, W2 LDS transpose) -> f2bT + s2 + F1b/F2b (BND).
// ---------------------------------------------------------------------------
__global__ __launch_bounds__(128)
void k_feats2(const unsigned short* __restrict__ hcatb, const float* __restrict__ W2,
              const float* __restrict__ as2, const float* __restrict__ an2,
              unsigned short* __restrict__ f2bT, float* __restrict__ s2,
              float* __restrict__ F1b, float* __restrict__ F2b)
{
    __shared__ __align__(16) unsigned short w2T[NCLS][520];
    const int t = threadIdx.x, wv = t >> 6, lane = t & 63;
    const int q = lane >> 4, n = lane & 15;
    #pragma unroll
    for (int i = 0; i < 16; ++i) {
        const int f4 = t + 128 * i;
        const float4 v = ((const float4*)W2)[f4];
        const int k = f4 >> 2, c0 = (f4 & 3) * 4;
        w2T[c0 + 0][k] = f2bf(v.x); w2T[c0 + 1][k] = f2bf(v.y);
        w2T[c0 + 2][k] = f2bf(v.z); w2T[c0 + 3][k] = f2bf(v.w);
    }
    __syncthreads();

    const int R0 = blockIdx.x * 32;
    const int row = R0 + wv * 16 + n;
    const unsigned short* ap = hcatb + (size_t)row * NFEAT;
    f32x4 acc = {0.f, 0.f, 0.f, 0.f};
    #pragma unroll 4
    for (int k0 = 0; k0 < NFEAT; k0 += 32) {
        const bf16x8 af = *(const bf16x8*)(ap + k0 + q * 8);
        const bf16x8 bf = *(const bf16x8*)&w2T[n][k0 + q * 8];
        acc = __builtin_amdgcn_mfma_f32_16x16x32_bf16(af, bf, acc, 0, 0, 0);
    }
    uint2 w;
    w.x = pkbf(acc[0], acc[1]);
    w.y = pkbf(acc[2], acc[3]);
    *(uint2*)(f2bT + (size_t)n * NN + R0 + wv * 16 + q * 4) = w;
    const float asv = as2[n], anv = an2[n];
    #pragma unroll
    for (int i = 0; i < 4; ++i) {
        float ps = acc[i] * asv, pn = acc[i] * anv;
        #pragma unroll
        for (int off = 8; off > 0; off >>= 1) {
            ps += __shfl_xor(ps, off, 64);
            pn += __shfl_xor(pn, off, 64);
        }
        if (n == 0) {
            const int idx = R0 + wv * 16 + q * 4 + i;
            s2[idx] = ps;
            F1b[idx] = __expf(pn - BND);
            F2b[idx] = __expf(0.2f * (pn - BND));
        }
    }
}

// ---------------------------------------------------------------------------
// Layer-2 aggregation + relu + log_softmax. 1024 thr = 16 wave j-sixteenths.
// ---------------------------------------------------------------------------
__global__ __launch_bounds__(1024)
void k_gat2(const unsigned short* __restrict__ f2bT, const float* __restrict__ s2,
            const float* __restrict__ F1, const float* __restrict__ F2,
            const unsigned long long* __restrict__ abits, const float* __restrict__ b2,
            float* __restrict__ out)
{
    __shared__ float cmb[16][16][17];
    __shared__ float lw[16][16];
    const int t = threadIdx.x, wv = t >> 6, lane = t & 63;
    const int q = lane >> 4, n = lane & 15;
    const int R0 = blockIdx.x * 16, row = R0 + n;
    const float v = s2[row] + BND, mhat = leaky(v);
    const float E1 = __expf(v - mhat), E2 = __expf(0.2f * v - mhat);
    const unsigned long long* arow = abits + (size_t)row * 64;

    f32x4 acc = {0.f, 0.f, 0.f, 0.f};
    float lsum = 0.f;
    const int jbeg = wv * 256;
    for (int j0 = jbeg; j0 < jbeg + 256; j0 += 64) {
        const unsigned long long a64 = arow[j0 >> 6];
        #pragma unroll
        for (int ch = 0; ch < 2; ++ch) {
            const int kb = ch * 32 + q * 8;
            const float4 f1a = *(const float4*)(F1 + j0 + kb);
            const float4 f1b = *(const float4*)(F1 + j0 + kb + 4);
            const float4 f2a = *(const float4*)(F2 + j0 + kb);
            const float4 f2b = *(const float4*)(F2 + j0 + kb + 4);
            const float F1v[8] = {f1a.x, f1a.y, f1a.z, f1a.w, f1b.x, f1b.y, f1b.z, f1b.w};
            const float F2v[8] = {f2a.x, f2a.y, f2a.z, f2a.w, f2b.x, f2b.y, f2b.z, f2b.w};
            const unsigned b8 = (unsigned)(a64 >> kb) & 0xffu;
            unsigned au[4];
            #pragma unroll
            for (int jp = 0; jp < 4; ++jp) {
                float p0 = fmaxf(E1 * F1v[2*jp],   E2 * F2v[2*jp]);
                float p1 = fmaxf(E1 * F1v[2*jp+1], E2 * F2v[2*jp+1]);
                p0 = ((b8 >> (2*jp)) & 1u) ? p0 : 0.f;
                p1 = ((b8 >> (2*jp+1)) & 1u) ? p1 : 0.f;
                lsum += p0 + p1;
                au[jp] = pkbf(p0, p1);
            }
            const bf16x8 af = mk8(au[0], au[1], au[2], au[3]);
            const bf16x8 bf = *(const bf16x8*)(f2bT + (size_t)n * NN + j0 + kb);
            acc = __builtin_amdgcn_mfma_f32_16x16x32_bf16(af, bf, acc, 0, 0, 0);
        }
    }
    lsum += __shfl_xor(lsum, 16, 64);
    lsum += __shfl_xor(lsum, 32, 64);
    #pragma unroll
    for (int i = 0; i < 4; ++i) cmb[wv][q * 4 + i][n] = acc[i];
    if (q == 0) lw[wv][n] = lsum;
    __syncthreads();

    if (t < 256) {
        const int r = t >> 4, c = t & 15;
        float tot = 0.f, lt = 0.f;
        #pragma unroll
        for (int w16 = 0; w16 < 16; ++w16) { tot += cmb[w16][r][c]; lt += lw[w16][r]; }
        float val = fmaxf(tot / lt + b2[c], 0.f);
        float mx = val;
        #pragma unroll
        for (int off = 1; off < 16; off <<= 1) mx = fmaxf(mx, __shfl_xor(mx, off, 64));
        const float e = __expf(val - mx);
        float se = e;
        #pragma unroll
        for (int off = 1; off < 16; off <<= 1) se += __shfl_xor(se, off, 64);
        out[(size_t)(R0 + r) * NCLS + c] = val - mx - __logf(se);
    }
}

// ---------------------------------------------------------------------------
extern "C" void kernel_launch(void* const* d_in, const int* in_sizes, int n_in,
                              void* d_out, int out_size, void* d_ws, size_t ws_size,
                              hipStream_t stream)
{
    const float* x   = (const float*)d_in[0];
    const int*   adj = (const int*)  d_in[1];
    const float* W1  = (const float*)d_in[2];
    const float* b1  = (const float*)d_in[3];
    const float* as1 = (const float*)d_in[4];
    const float* an1 = (const float*)d_in[5];
    const float* W2  = (const float*)d_in[6];
    const float* b2  = (const float*)d_in[7];
    const float* as2 = (const float*)d_in[8];
    const float* an2 = (const float*)d_in[9];
    float* out = (float*)d_out;

    char* ws = (char*)d_ws;
    unsigned long long* abits = (unsigned long long*)(ws);            // 2 MB
    unsigned short* f1bT  = (unsigned short*)(ws + (2u << 20));       // 4 MB (f16)
    unsigned short* xh    = (unsigned short*)(ws + (6u << 20));       // 4 MB (f16)
    unsigned short* hcatb = xh;   // disjoint lifetime: xh dead after k_feats1
    unsigned short* w1f   = (unsigned short*)(ws + (10u << 20));      // 512 KB (f16)
    char* ws2 = ws + (10u << 20) + (512u << 10);
    float* s1   = (float*)(ws2);                                      // 128 KB
    float* nb1  = (float*)(ws2 + (128u << 10));                       // 128 KB
    unsigned short* F1h = (unsigned short*)(ws2 + (256u << 10));      // 64 KB
    unsigned short* F2h = (unsigned short*)(ws2 + (320u << 10));      // 64 KB
    unsigned short* f2bT = (unsigned short*)(ws2 + (384u << 10));     // 128 KB
    float* s2   = (float*)(ws2 + (512u << 10));                       // 16 KB
    float* F1b  = (float*)(ws2 + (528u << 10));                       // 16 KB
    float* F2b  = (float*)(ws2 + (544u << 10));                       // 16 KB
    float* nbmax1 = (float*)(ws2 + (560u << 10));                     // 32 B

    k_prep  <<<dim3(NN + 64 + 512), 256, 0, stream>>>(adj, abits, W1, w1f, x, xh);
    k_feats1<<<dim3(NN / 64, H1),   256, 0, stream>>>(xh, w1f, as1, an1, f1bT, s1, nb1);
    k_fact1 <<<dim3(H1),            256, 0, stream>>>(nb1, F1h, F2h, nbmax1);
    k_gat1  <<<dim3(NN / 64, H1),   512, 0, stream>>>(f1bT, s1, F1h, F2h, abits, b1, nbmax1, hcatb);
    k_feats2<<<dim3(NN / 32),       128, 0, stream>>>(hcatb, W2, as2, an2, f2bT, s2, F1b, F2b);
    k_gat2  <<<dim3(NN / 16),       1024, 0, stream>>>(f2bT, s2, F1b, F2b, abits, b2, out);
}